// Round 1
// baseline (273.204 us; speedup 1.0000x reference)
//
#include <hip/hip_runtime.h>
#include <hip/hip_bf16.h>

// dims
#define BB 2
#define LL 2048
#define DD 1024
#define HIDD 1024
#define HH 8
// DQK=64, DUV=128, OUT_DIM=3072

typedef float f32x4 __attribute__((ext_vector_type(4)));
typedef short s16x8 __attribute__((ext_vector_type(8)));
typedef unsigned short u16x4 __attribute__((ext_vector_type(4)));

__device__ __forceinline__ float bf2f(unsigned short u) {
    union { unsigned int i; float f; } x; x.i = ((unsigned int)u) << 16; return x.f;
}
__device__ __forceinline__ unsigned short f2bf(float f) {
    union { float f; unsigned int i; } x; x.f = f;
    unsigned int r = x.i + 0x7FFFu + ((x.i >> 16) & 1u);
    return (unsigned short)(r >> 16);
}
__device__ __forceinline__ float silu(float v) {
    return v / (1.f + __expf(-v));
}

// ---------------------------------------------------------------------------
// Kernel 1: h = silu(X @ W_uvqk^T + b); route columns into U, Vt, Q(*scale), K
// X [4096][1024] f32, W [3072][1024] f32 (row-major = [N][K])
// U bf16 [4096][1024]; Vt bf16 [B][H][128][2048]; Q/K bf16 [B][H][2048][64]
// ---------------------------------------------------------------------------
__global__ __launch_bounds__(256) void gemm_uvqk(
    const float* __restrict__ X, const float* __restrict__ W,
    const float* __restrict__ bias,
    unsigned short* __restrict__ U, unsigned short* __restrict__ Vt,
    unsigned short* __restrict__ Q, unsigned short* __restrict__ K)
{
    __shared__ unsigned short sA[128][40];
    __shared__ unsigned short sB[128][40];
    const int tid = threadIdx.x;
    const int wv = tid >> 6, lane = tid & 63;
    const int g = lane >> 4, lr = lane & 15;
    const int m0 = blockIdx.x * 128, n0 = blockIdx.y * 128;
    const int wr = (wv >> 1) * 64, wc = (wv & 1) * 64;
    f32x4 acc[4][4] = {};

    for (int k0 = 0; k0 < 1024; k0 += 32) {
        __syncthreads();
        #pragma unroll
        for (int it = 0; it < 4; ++it) {
            int idx = it * 256 + tid;            // float4 index, 1024 total
            int row = idx >> 3, c4 = (idx & 7) * 4;
            f32x4 a = *reinterpret_cast<const f32x4*>(&X[(m0 + row) * 1024 + k0 + c4]);
            f32x4 b = *reinterpret_cast<const f32x4*>(&W[(n0 + row) * 1024 + k0 + c4]);
            u16x4 ua, ub;
            #pragma unroll
            for (int j = 0; j < 4; ++j) { ua[j] = f2bf(a[j]); ub[j] = f2bf(b[j]); }
            *reinterpret_cast<u16x4*>(&sA[row][c4]) = ua;
            *reinterpret_cast<u16x4*>(&sB[row][c4]) = ub;
        }
        __syncthreads();
        s16x8 afr[4], bfr[4];
        #pragma unroll
        for (int i = 0; i < 4; ++i)
            afr[i] = *reinterpret_cast<const s16x8*>(&sA[wr + i * 16 + lr][g * 8]);
        #pragma unroll
        for (int i = 0; i < 4; ++i)
            bfr[i] = *reinterpret_cast<const s16x8*>(&sB[wc + i * 16 + lr][g * 8]);
        #pragma unroll
        for (int mi = 0; mi < 4; ++mi)
            #pragma unroll
            for (int ni = 0; ni < 4; ++ni)
                acc[mi][ni] = __builtin_amdgcn_mfma_f32_16x16x32_bf16(
                    afr[mi], bfr[ni], acc[mi][ni], 0, 0, 0);
    }

    #pragma unroll
    for (int ni = 0; ni < 4; ++ni) {
        int n = n0 + wc + ni * 16 + lr;
        float bn = bias[n];
        #pragma unroll
        for (int mi = 0; mi < 4; ++mi) {
            #pragma unroll
            for (int r = 0; r < 4; ++r) {
                int m = m0 + wr + mi * 16 + g * 4 + r;
                float v = silu(acc[mi][ni][r] + bn);
                int b = m >> 11, l = m & 2047;
                if (n < 1024) {
                    U[m * 1024 + n] = f2bf(v);
                } else if (n < 2048) {
                    int dd = n - 1024, h = dd >> 7, d = dd & 127;
                    Vt[(((b * 8 + h) * 128 + d) << 11) + l] = f2bf(v);
                } else if (n < 2560) {
                    int dd = n - 2048, h = dd >> 6, d = dd & 63;
                    Q[((((b * 8 + h) << 11) + l) << 6) + d] = f2bf(v * 0.125f); // bake 1/sqrt(64)
                } else {
                    int dd = n - 2560, h = dd >> 6, d = dd & 63;
                    K[((((b * 8 + h) << 11) + l) << 6) + d] = f2bf(v);
                }
            }
        }
    }
}

// ---------------------------------------------------------------------------
// Kernel 2: pointwise-silu attention with bucketized relative-time bias.
// Y[b][i][h*128+d] = sum_{j<=i} silu(q_i.k_j + tb[bucket(|t_i-t_j|)][h]) * v[j][d]
// Block: 256 thr = 4 waves; wave w owns 16 i-rows. Paired i-tiles (ti, 31-ti)
// for perfect balance. No barriers in the j-loop (waves independent).
// ---------------------------------------------------------------------------
__global__ __launch_bounds__(256) void attn(
    const unsigned short* __restrict__ Q, const unsigned short* __restrict__ K,
    const unsigned short* __restrict__ Vt, const int* __restrict__ TS,
    const float* __restrict__ TB, float* __restrict__ Y)
{
    __shared__ int bndRaw[63];
    __shared__ int bnd[64];
    __shared__ float tb[64];
    __shared__ unsigned short sP[4][16][72];   // per-wave P-tile transpose buffer

    const int tid = threadIdx.x, wv = tid >> 6, lane = tid & 63;
    const int g = lane >> 4, lr = lane & 15;
    const int bh = blockIdx.y, b = bh >> 3, h = bh & 7;

    if (tid < 63) {
        double step = log(7776000.0) / 62.0;   // MAX_SPAN = 86400*90
        double v = exp(step * (double)tid);
        if (v < 1.0) v = 1.0;
        bndRaw[tid] = (int)floor(v);
    }
    if (tid < 64) tb[tid] = TB[tid * 8 + h];
    __syncthreads();
    if (tid == 0) {                             // unique()
        int cnt = 0, prev = -1;
        for (int i = 0; i < 63; ++i) {
            int x = bndRaw[i];
            if (x != prev) { bnd[cnt++] = x; prev = x; }
        }
        for (; cnt < 64; ++cnt) bnd[cnt] = 0x7FFFFFFF;  // sentinel pad
    }
    __syncthreads();

    const unsigned short* qb = Q + (size_t)(bh << 11) * 64;
    const unsigned short* kb = K + (size_t)(bh << 11) * 64;
    const unsigned short* vtb = Vt + (size_t)(bh << 7) * 2048;
    const int* ts = TS + (b << 11);

    for (int rep = 0; rep < 2; ++rep) {
        const int ti = (rep == 0) ? (int)blockIdx.x : 31 - (int)blockIdx.x;
        const int i0 = ti * 64;
        const int irow = i0 + wv * 16;

        s16x8 aq[2];
        #pragma unroll
        for (int kk = 0; kk < 2; ++kk)
            aq[kk] = *reinterpret_cast<const s16x8*>(&qb[(irow + lr) * 64 + kk * 32 + g * 8]);
        int trow[4];
        #pragma unroll
        for (int r = 0; r < 4; ++r) trow[r] = ts[irow + g * 4 + r];

        f32x4 accy[8] = {};
        for (int jt = 0; jt <= ti; ++jt) {
            const int j0 = jt * 64;
            f32x4 s[4] = {};
            #pragma unroll
            for (int ni = 0; ni < 4; ++ni) {
                #pragma unroll
                for (int kk = 0; kk < 2; ++kk) {
                    s16x8 bk = *reinterpret_cast<const s16x8*>(
                        &kb[(j0 + ni * 16 + lr) * 64 + kk * 32 + g * 8]);
                    s[ni] = __builtin_amdgcn_mfma_f32_16x16x32_bf16(aq[kk], bk, s[ni], 0, 0, 0);
                }
            }
            // bias + silu + causal mask, transpose via per-wave LDS
            #pragma unroll
            for (int ni = 0; ni < 4; ++ni) {
                int j = j0 + ni * 16 + lr;
                int tj = ts[j];
                #pragma unroll
                for (int r = 0; r < 4; ++r) {
                    int i = irow + g * 4 + r;
                    int td = trow[r] - tj; td = td < 0 ? -td : td; if (td < 1) td = 1;
                    int pos = 0;
                    #pragma unroll
                    for (int st = 32; st; st >>= 1)
                        if (bnd[pos + st - 1] < td) pos += st;
                    float v = silu(s[ni][r] + tb[pos]);
                    if (j > i) v = 0.f;
                    sP[wv][g * 4 + r][ni * 16 + lr] = f2bf(v);
                }
            }
            s16x8 apv[2];
            #pragma unroll
            for (int kk = 0; kk < 2; ++kk)
                apv[kk] = *reinterpret_cast<const s16x8*>(&sP[wv][lr][kk * 32 + g * 8]);
            #pragma unroll
            for (int di = 0; di < 8; ++di) {
                #pragma unroll
                for (int kk = 0; kk < 2; ++kk) {
                    s16x8 bv = *reinterpret_cast<const s16x8*>(
                        &vtb[(di * 16 + lr) * 2048 + j0 + kk * 32 + g * 8]);
                    accy[di] = __builtin_amdgcn_mfma_f32_16x16x32_bf16(apv[kk], bv, accy[di], 0, 0, 0);
                }
            }
        }
        #pragma unroll
        for (int di = 0; di < 8; ++di)
            #pragma unroll
            for (int r = 0; r < 4; ++r) {
                int i = irow + g * 4 + r;
                Y[(size_t)((b << 11) + i) * 1024 + h * 128 + di * 16 + lr] = accy[di][r];
            }
    }
}

// ---------------------------------------------------------------------------
// Kernel 3: RMSNorm over HID=1024 then U-gate; emit bf16 YP.
// ---------------------------------------------------------------------------
__global__ __launch_bounds__(256) void rmsnorm_gate(
    const float* __restrict__ Y, const unsigned short* __restrict__ U,
    const float* __restrict__ rw, unsigned short* __restrict__ YP)
{
    __shared__ float red[4];
    const int row = blockIdx.x, tid = threadIdx.x;
    f32x4 v = *reinterpret_cast<const f32x4*>(&Y[(size_t)row * 1024 + tid * 4]);
    float ss = v[0] * v[0] + v[1] * v[1] + v[2] * v[2] + v[3] * v[3];
    #pragma unroll
    for (int off = 32; off; off >>= 1) ss += __shfl_down(ss, off);
    if ((tid & 63) == 0) red[tid >> 6] = ss;
    __syncthreads();
    float rms = rsqrtf((red[0] + red[1] + red[2] + red[3]) * (1.f / 1024.f) + 1e-6f);
    #pragma unroll
    for (int j = 0; j < 4; ++j) {
        int c = tid * 4 + j;
        float o = v[j] * rms * rw[c] * bf2f(U[(size_t)row * 1024 + c]);
        YP[(size_t)row * 1024 + c] = f2bf(o);
    }
}

// ---------------------------------------------------------------------------
// Kernel 4: OUT = YP @ W_o^T + b_o.   YP bf16 [4096][1024], W_o f32 [1024][1024]
// ---------------------------------------------------------------------------
__global__ __launch_bounds__(256) void gemm_out(
    const unsigned short* __restrict__ YP, const float* __restrict__ Wo,
    const float* __restrict__ bo, float* __restrict__ OUT)
{
    __shared__ unsigned short sA[128][40];
    __shared__ unsigned short sB[128][40];
    const int tid = threadIdx.x;
    const int wv = tid >> 6, lane = tid & 63;
    const int g = lane >> 4, lr = lane & 15;
    const int m0 = blockIdx.x * 128, n0 = blockIdx.y * 128;
    const int wr = (wv >> 1) * 64, wc = (wv & 1) * 64;
    f32x4 acc[4][4] = {};

    for (int k0 = 0; k0 < 1024; k0 += 32) {
        __syncthreads();
        #pragma unroll
        for (int it = 0; it < 2; ++it) {
            int idx = it * 256 + tid;            // ushort8 index, 512 total
            int row = idx >> 2, c8 = (idx & 3) * 8;
            s16x8 a = *reinterpret_cast<const s16x8*>(&YP[(size_t)(m0 + row) * 1024 + k0 + c8]);
            *reinterpret_cast<s16x8*>(&sA[row][c8]) = a;
        }
        #pragma unroll
        for (int it = 0; it < 4; ++it) {
            int idx = it * 256 + tid;
            int row = idx >> 3, c4 = (idx & 7) * 4;
            f32x4 bv = *reinterpret_cast<const f32x4*>(&Wo[(size_t)(n0 + row) * 1024 + k0 + c4]);
            u16x4 ub;
            #pragma unroll
            for (int j = 0; j < 4; ++j) ub[j] = f2bf(bv[j]);
            *reinterpret_cast<u16x4*>(&sB[row][c4]) = ub;
        }
        __syncthreads();
        s16x8 afr[4], bfr[4];
        #pragma unroll
        for (int i = 0; i < 4; ++i)
            afr[i] = *reinterpret_cast<const s16x8*>(&sA[wr + i * 16 + lr][g * 8]);
        #pragma unroll
        for (int i = 0; i < 4; ++i)
            bfr[i] = *reinterpret_cast<const s16x8*>(&sB[wc + i * 16 + lr][g * 8]);
        #pragma unroll
        for (int mi = 0; mi < 4; ++mi)
            #pragma unroll
            for (int ni = 0; ni < 4; ++ni)
                acc[mi][ni] = __builtin_amdgcn_mfma_f32_16x16x32_bf16(
                    afr[mi], bfr[ni], acc[mi][ni], 0, 0, 0);
    }

    #pragma unroll
    for (int ni = 0; ni < 4; ++ni) {
        int n = n0 + wc + ni * 16 + lr;
        float bn = bo[n];
        #pragma unroll
        for (int mi = 0; mi < 4; ++mi)
            #pragma unroll
            for (int r = 0; r < 4; ++r) {
                int m = m0 + wr + mi * 16 + g * 4 + r;
                OUT[(size_t)m * 1024 + n] = acc[mi][ni][r] + bn;
            }
    }
}

// ---------------------------------------------------------------------------
extern "C" void kernel_launch(void* const* d_in, const int* in_sizes, int n_in,
                              void* d_out, int out_size, void* d_ws, size_t ws_size,
                              hipStream_t stream) {
    const float* X     = (const float*)d_in[0];
    const int*   TS    = (const int*)d_in[1];
    // d_in[2] = attn_mask (causal tril) — recomputed on device, not read
    const float* Wuvqk = (const float*)d_in[3];
    const float* buvqk = (const float*)d_in[4];
    const float* TB    = (const float*)d_in[5];
    const float* Wo    = (const float*)d_in[6];
    const float* bo    = (const float*)d_in[7];
    const float* rw    = (const float*)d_in[8];
    float* OUT = (float*)d_out;

    char* ws = (char*)d_ws;
    unsigned short* Qb = (unsigned short*)(ws);               //  4 MiB  [2][8][2048][64]
    unsigned short* Kb = (unsigned short*)(ws + 4194304);     //  4 MiB
    unsigned short* Vt = (unsigned short*)(ws + 8388608);     //  8 MiB  [2][8][128][2048]
    unsigned short* Ub = (unsigned short*)(ws + 16777216);    //  8 MiB  [4096][1024]
    float*          Yb = (float*)(ws + 25165824);             // 16 MiB  [4096][1024]
    unsigned short* YP = (unsigned short*)(ws + 41943040);    //  8 MiB  [4096][1024]

    gemm_uvqk<<<dim3(32, 24), 256, 0, stream>>>(X, Wuvqk, buvqk, Ub, Vt, Qb, Kb);
    attn<<<dim3(16, 16), 256, 0, stream>>>(Qb, Kb, Vt, TS, TB, Yb);
    rmsnorm_gate<<<4096, 256, 0, stream>>>(Yb, Ub, rw, YP);
    gemm_out<<<dim3(32, 8), 256, 0, stream>>>(YP, Wo, bo, OUT);
}